// Round 9
// baseline (170.022 us; speedup 1.0000x reference)
//
#include <hip/hip_runtime.h>
#include <hip/hip_bf16.h>
#include <cstddef>

typedef __attribute__((ext_vector_type(8))) short short8;
typedef __attribute__((ext_vector_type(4))) short short4v;
typedef __attribute__((ext_vector_type(4))) float floatx4;
typedef __hip_bfloat16 bf16;

#define NB 8
#define NC 256
#define ND 128
#define NN 3072
#define NCH 32            /* n-chunks for G = x x^T (96 each) */
#define BN_EPS 1e-5f

static __device__ __forceinline__ short f2s(float v) {
    bf16 h = __float2bfloat16(v);
    return *reinterpret_cast<short*>(&h);
}
static __device__ __forceinline__ float s2f(short s) {
    unsigned int u = ((unsigned int)(unsigned short)s) << 16;
    return __uint_as_float(u);
}
// load 8 consecutive fp32, convert to bf16 short8 (MFMA operand)
static __device__ __forceinline__ short8 ld8cvt(const float* p) {
    floatx4 a = *(const floatx4*)p, b = *(const floatx4*)(p + 4);
    short8 r;
    r[0] = f2s(a[0]); r[1] = f2s(a[1]); r[2] = f2s(a[2]); r[3] = f2s(a[3]);
    r[4] = f2s(b[0]); r[5] = f2s(b[1]); r[6] = f2s(b[2]); r[7] = f2s(b[3]);
    return r;
}

// ---------------------------------------------------------------------------
// front: grid 384 x 512 thr.
//   blk 0..255  -> G-partial: stages x[256 c][96 n] -> LDS bf16 once,
//     computes full 256x256 partial X.X^T, stores Gpart bf16 TRANSPOSED
//     ([col][row]) -- valid because each per-chunk partial is symmetric --
//     so each thread's 4 acc values (4 consecutive rows, fixed col) become
//     one short4v store (32x 8B stores vs 128x 2B scalar stores).
//   blk 256..383 -> sx[b][c] = sum_n x[b,c,n]
// ---------------------------------------------------------------------------
__global__ __launch_bounds__(512, 2)
void front_kernel(const float* __restrict__ x, short* __restrict__ GpartS,
                  float* __restrict__ sx)
{
    __shared__ short Xs[256][104];   // 53.2 KB
    int blk = blockIdx.x;
    int t = threadIdx.x;

    if (blk >= 256) {     // ---- sx
        int bs = blk - 256;
        int b = bs >> 4;
        int c0 = (bs & 15) * 16;
        int r = t >> 5;             // 0..15
        int w32 = t & 31;
        const float* xr = x + ((size_t)b * NC + c0 + r) * NN;
        float s = 0.f;
#pragma unroll
        for (int k = 0; k < 24; ++k) {
            floatx4 v = *(const floatx4*)(xr + (size_t)(w32 + k * 32) * 4);
            s += v[0] + v[1] + v[2] + v[3];
        }
#pragma unroll
        for (int off = 16; off; off >>= 1) s += __shfl_down(s, off, 32);
        if (w32 == 0) sx[b * NC + c0 + r] = s;
        return;
    }

    // ---- G partial
    int b = blk >> 5;
    int n0 = (blk & 31) * 96;
    int lane = t & 63, wave = t >> 6;
    int lm = lane & 15, lh = lane >> 4, lk = lh * 8;
    int wr = wave >> 2;             // 0..1: row half (128)
    int wc = wave & 3;              // 0..3: col quarter (64)
    const float* xb = x + (size_t)b * NC * NN;

    floatx4 xv[12];
#pragma unroll
    for (int p = 0; p < 12; ++p) {
        int id = p * 512 + t;        // float4 id over 6144
        int row = id / 24;
        int c4 = (id % 24) * 4;
        xv[p] = *(const floatx4*)(xb + (size_t)row * NN + n0 + c4);
    }
#pragma unroll
    for (int p = 0; p < 12; ++p) {
        int id = p * 512 + t;
        int row = id / 24;
        int c4 = (id % 24) * 4;
        short4v o;
#pragma unroll
        for (int j = 0; j < 4; ++j) o[j] = f2s(xv[p][j]);
        *(short4v*)&Xs[row][c4] = o;
    }
    __syncthreads();

    floatx4 zero = {0.f, 0.f, 0.f, 0.f};
    floatx4 acc[8][4];
#pragma unroll
    for (int i = 0; i < 8; ++i)
#pragma unroll
        for (int j = 0; j < 4; ++j) acc[i][j] = zero;

#pragma unroll
    for (int kk = 0; kk < 96; kk += 32) {
        short8 af[8], bf[4];
#pragma unroll
        for (int i = 0; i < 8; ++i)
            af[i] = *(const short8*)&Xs[wr * 128 + i * 16 + lm][kk + lk];
#pragma unroll
        for (int j = 0; j < 4; ++j)
            bf[j] = *(const short8*)&Xs[wc * 64 + j * 16 + lm][kk + lk];
#pragma unroll
        for (int i = 0; i < 8; ++i)
#pragma unroll
            for (int j = 0; j < 4; ++j)
                acc[i][j] = __builtin_amdgcn_mfma_f32_16x16x32_bf16(
                    af[i], bf[j], acc[i][j], 0, 0, 0);
    }

    // transposed store (partial is symmetric): 4 consecutive rows per lane
    short* Gf = GpartS + (size_t)blk * 65536;
#pragma unroll
    for (int i = 0; i < 8; ++i) {
#pragma unroll
        for (int j = 0; j < 4; ++j) {
            int row0 = wr * 128 + i * 16 + lh * 4;
            int col  = wc * 64 + j * 16 + lm;
            short4v o;
#pragma unroll
            for (int rr = 0; rr < 4; ++rr) o[rr] = f2s(acc[i][j][rr]);
            *(short4v*)(Gf + (size_t)col * NC + row0) = o;
        }
    }
}

// ---------------------------------------------------------------------------
// gredUV: grid 521 x 256 thr.
//   blk 0..511   -> G[b] = sum_p GpartS (fp32 out + bf16 copy Gb16)
//   blk 512..515 -> U = w_w . g_w   (fp32 + bf16 copy Ub16)
//   blk 516..519 -> VT = theta_w^T phi_w  (fp32 + bf16 copy VTb16)
//   blk 520      -> q, u1, vb vectors
// ---------------------------------------------------------------------------
__global__ __launch_bounds__(256)
void gredUV_kernel(const short* __restrict__ GpartS,
                   const float* __restrict__ g_w, const float* __restrict__ g_b,
                   const float* __restrict__ theta_w, const float* __restrict__ theta_b,
                   const float* __restrict__ phi_w, const float* __restrict__ phi_b,
                   const float* __restrict__ w_w,
                   float* __restrict__ G, short* __restrict__ Gb16,
                   float* __restrict__ U, short* __restrict__ Ub16,
                   float* __restrict__ VT, short* __restrict__ VTb16,
                   float* __restrict__ qv, float* __restrict__ u1v,
                   float* __restrict__ vbv)
{
    __shared__ short TA[128][72];
    __shared__ short TB[128][72];
    int blk = blockIdx.x;
    int t = threadIdx.x;

    if (blk < 512) {          // ---- G reduce
        int idx = blk * 256 + t;            // float4-output id, 131072 total
        int b = idx >> 14;
        int fo = (idx & 16383) * 4;
        const short* src = GpartS + (size_t)b * 32 * 65536 + fo;
        floatx4 s = {0.f, 0.f, 0.f, 0.f};
#pragma unroll 8
        for (int p = 0; p < NCH; ++p) {
            short4v v = *(const short4v*)(src + (size_t)p * 65536);
            s[0] += s2f(v[0]); s[1] += s2f(v[1]);
            s[2] += s2f(v[2]); s[3] += s2f(v[3]);
        }
        *(floatx4*)(G + (size_t)b * 65536 + fo) = s;
        short4v o;
#pragma unroll
        for (int j = 0; j < 4; ++j) o[j] = f2s(s[j]);
        *(short4v*)(Gb16 + (size_t)b * 65536 + fo) = o;
        return;
    }
    if (blk == 520) {         // ---- small vectors
        int c = t;
        float s_q = 0.f, s_vb = 0.f, s_u1 = 0.f;
#pragma unroll
        for (int e = 0; e < 128; ++e) {
            s_q  += phi_w[(size_t)e * NC + c] * theta_b[e];
            s_vb += theta_w[(size_t)e * NC + c] * phi_b[e];
        }
        const float* wr_ = w_w + (size_t)c * ND;
#pragma unroll
        for (int d = 0; d < 32; ++d) {
            floatx4 v = *(const floatx4*)(wr_ + d * 4);
            floatx4 gb = *(const floatx4*)(g_b + d * 4);
            s_u1 += v[0]*gb[0] + v[1]*gb[1] + v[2]*gb[2] + v[3]*gb[3];
        }
        qv[c] = s_q; vbv[c] = s_vb; u1v[c] = s_u1;
        return;
    }

    int lane = t & 63, wave = t >> 6;
    int lm = lane & 15, lh = lane >> 4, lk = lh * 8;
    int wr = wave >> 1, wc = wave & 1;
    floatx4 zero = {0.f, 0.f, 0.f, 0.f};
    floatx4 acc[4][4];
#pragma unroll
    for (int i = 0; i < 4; ++i)
#pragma unroll
        for (int j = 0; j < 4; ++j) acc[i][j] = zero;

    if (blk < 516) {          // ---- U tile (K = d, halved staging)
        int ti = blk - 512, tr = ti >> 1, tc = ti & 1;
#pragma unroll
        for (int dh = 0; dh < 2; ++dh) {
            __syncthreads();
#pragma unroll
            for (int p = 0; p < 8; ++p) {
                int id = p * 256 + t;        // float4 id over 2048
                int dl = id >> 5;            // 0..63
                int c4 = (id & 31) * 4;
                floatx4 v = *(const floatx4*)(g_w + (size_t)(dh * 64 + dl) * NC
                                              + tc * 128 + c4);
#pragma unroll
                for (int j = 0; j < 4; ++j) TB[c4 + j][dl] = f2s(v[j]);
            }
            __syncthreads();
#pragma unroll
            for (int kk = 0; kk < 64; kk += 32) {
                short8 af[4], bf[4];
#pragma unroll
                for (int i = 0; i < 4; ++i)
                    af[i] = ld8cvt(w_w + (size_t)(tr * 128 + wr * 64 + i * 16 + lm) * ND
                                   + dh * 64 + kk + lk);
#pragma unroll
                for (int j = 0; j < 4; ++j)
                    bf[j] = *(const short8*)&TB[wc * 64 + j * 16 + lm][kk + lk];
#pragma unroll
                for (int i = 0; i < 4; ++i)
#pragma unroll
                    for (int j = 0; j < 4; ++j)
                        acc[i][j] = __builtin_amdgcn_mfma_f32_16x16x32_bf16(
                            af[i], bf[j], acc[i][j], 0, 0, 0);
            }
        }
#pragma unroll
        for (int i = 0; i < 4; ++i)
#pragma unroll
            for (int j = 0; j < 4; ++j)
#pragma unroll
                for (int rr = 0; rr < 4; ++rr) {
                    size_t off = (size_t)(tr * 128 + wr * 64 + i * 16 + lh * 4 + rr) * NC
                               + tc * 128 + wc * 64 + j * 16 + lm;
                    float v = acc[i][j][rr];
                    U[off] = v; Ub16[off] = f2s(v);
                }
    } else {                  // ---- VT tile (K = e, halved staging)
        int ti = blk - 516, tr = ti >> 1, tc = ti & 1;
#pragma unroll
        for (int eh = 0; eh < 2; ++eh) {
            __syncthreads();
#pragma unroll
            for (int p = 0; p < 8; ++p) {
                int id = p * 256 + t;
                int el = id >> 5;            // 0..63
                int c4 = (id & 31) * 4;
                floatx4 a = *(const floatx4*)(theta_w + (size_t)(eh * 64 + el) * NC
                                              + tr * 128 + c4);
                floatx4 bb = *(const floatx4*)(phi_w + (size_t)(eh * 64 + el) * NC
                                               + tc * 128 + c4);
#pragma unroll
                for (int j = 0; j < 4; ++j) {
                    TA[c4 + j][el] = f2s(a[j]);
                    TB[c4 + j][el] = f2s(bb[j]);
                }
            }
            __syncthreads();
#pragma unroll
            for (int kk = 0; kk < 64; kk += 32) {
                short8 af[4], bf[4];
#pragma unroll
                for (int i = 0; i < 4; ++i)
                    af[i] = *(const short8*)&TA[wr * 64 + i * 16 + lm][kk + lk];
#pragma unroll
                for (int j = 0; j < 4; ++j)
                    bf[j] = *(const short8*)&TB[wc * 64 + j * 16 + lm][kk + lk];
#pragma unroll
                for (int i = 0; i < 4; ++i)
#pragma unroll
                    for (int j = 0; j < 4; ++j)
                        acc[i][j] = __builtin_amdgcn_mfma_f32_16x16x32_bf16(
                            af[i], bf[j], acc[i][j], 0, 0, 0);
            }
        }
#pragma unroll
        for (int i = 0; i < 4; ++i)
#pragma unroll
            for (int j = 0; j < 4; ++j)
#pragma unroll
                for (int rr = 0; rr < 4; ++rr) {
                    size_t off = (size_t)(tr * 128 + wr * 64 + i * 16 + lh * 4 + rr) * NC
                               + tc * 128 + wc * 64 + j * 16 + lm;
                    float v = acc[i][j][rr];
                    VT[off] = v; VTb16[off] = f2s(v);
                }
    }
}

// ---------------------------------------------------------------------------
// qf: grid 72 x 512 thr.
//   blk 0..63 -> Qf tile 64c x 128cp. Stage 1: Ts = U[64 rows].G (K=256,
//     bf16 global operands, depth-1 reg prefetch). Stage 2: Qf = Ts.VT^T.
//     Rank-1 + scale in epilogue.
//   blk 64..71 -> per-batch C2 (fp32 path).
// ---------------------------------------------------------------------------
__global__ __launch_bounds__(512, 2)
void qf_kernel(const float* __restrict__ G, const short* __restrict__ Gb16,
               const float* __restrict__ U, const short* __restrict__ Ub16,
               const float* __restrict__ VT, const short* __restrict__ VTb16,
               const float* __restrict__ qv, const float* __restrict__ u1v,
               const float* __restrict__ vbv, const float* __restrict__ sx,
               const float* __restrict__ phi_b, const float* __restrict__ theta_b,
               const float* __restrict__ w_b,
               const float* __restrict__ gamma, const float* __restrict__ beta,
               const float* __restrict__ mean, const float* __restrict__ var,
               short* __restrict__ QfB, float* __restrict__ C2g)
{
    __shared__ short Ts[64][264];          // 33.8 KB
    __shared__ float f0[256], f1[256], f2[256];
    int blk = blockIdx.x;
    int t = threadIdx.x;

    if (blk >= 64) {          // ---- C2 blocks (f0=q, f1=sx, f2=m)
        int b = blk - 64;
        if (t < 64) {
            *(floatx4*)&f0[t * 4] = *(const floatx4*)(qv + t * 4);
            *(floatx4*)&f1[t * 4] = *(const floatx4*)(sx + b * NC + t * 4);
        }
        __syncthreads();
        if (t < 256) {        // m = G q
            const float* Gr = G + (size_t)b * 65536 + (size_t)t * 256;
            float m = 0.f;
#pragma unroll
            for (int k = 0; k < 64; ++k) {
                floatx4 v = *(const floatx4*)(Gr + k * 4);
                m += v[0]*f0[k*4] + v[1]*f0[k*4+1] + v[2]*f0[k*4+2] + v[3]*f0[k*4+3];
            }
            f2[t] = m;
        }
        __syncthreads();
        if (t < 256) {
            float s1 = 0.f, s2 = 0.f;
#pragma unroll 8
            for (int k = 0; k < 256; ++k) s1 += f1[k] * f0[k];
#pragma unroll 8
            for (int e = 0; e < 128; ++e) s2 += phi_b[e] * theta_b[e];
            float um = 0.f, u2 = 0.f;
            const float* Ur = U + (size_t)t * 256;
#pragma unroll
            for (int k = 0; k < 64; ++k) {
                floatx4 u = *(const floatx4*)(Ur + k * 4);
                um += u[0]*f2[k*4] + u[1]*f2[k*4+1] + u[2]*f2[k*4+2] + u[3]*f2[k*4+3];
                u2 += u[0]*f1[k*4] + u[1]*f1[k*4+1] + u[2]*f1[k*4+2] + u[3]*f1[k*4+3];
            }
            float u1c = u1v[t];
            float c2raw = (um + u1c * s1 + (u2 + (float)NN * u1c) * s2) * (1.f / (float)NN);
            float iv = gamma[t] * rsqrtf(var[t] + BN_EPS);
            C2g[b * NC + t] = iv * (c2raw + w_b[t] - mean[t]) + beta[t];
        }
        return;
    }

    // ---- Qf tile blocks (f0=sx, f1=val[128], f2=u2l[64])
    int b = blk >> 3;
    int tile = blk & 7, tr = tile >> 1, tc = tile & 1;
    int lane = t & 63, wave = t >> 6;
    int lm = lane & 15, lh = lane >> 4, lk = lh * 8;
    const short* Gb = Gb16 + (size_t)b * 65536;
    floatx4 zero = {0.f, 0.f, 0.f, 0.f};

    if (t < 64) *(floatx4*)&f0[t * 4] = *(const floatx4*)(sx + b * NC + t * 4);
    __syncthreads();
    if (t < 128) {            // val[cp-local] = VT[tc*128+t] . sx
        const float* Rr = VT + (size_t)(tc * 128 + t) * NC;
        float s = 0.f;
#pragma unroll
        for (int k = 0; k < 64; ++k) {
            floatx4 v = *(const floatx4*)(Rr + k * 4);
            s += v[0]*f0[k*4] + v[1]*f0[k*4+1] + v[2]*f0[k*4+2] + v[3]*f0[k*4+3];
        }
        f1[t] = s;
    } else if (t < 192) {     // u2l[c-local] = U[tr*64+(t-128)] . sx
        const float* Rr = U + (size_t)(tr * 64 + (t - 128)) * NC;
        float s = 0.f;
#pragma unroll
        for (int k = 0; k < 64; ++k) {
            floatx4 v = *(const floatx4*)(Rr + k * 4);
            s += v[0]*f0[k*4] + v[1]*f0[k*4+1] + v[2]*f0[k*4+2] + v[3]*f0[k*4+3];
        }
        f2[t - 128] = s;
    }

    // ---- stage 1: Ts = U[tr*64 rows] . G  (64 x 256, K=256, prefetch d1)
    {
        int wvr = wave >> 2;      // 0..1: 32-row group
        int wvc = wave & 3;       // 0..3: 64-col group
        floatx4 acc[2][4];
#pragma unroll
        for (int i = 0; i < 2; ++i)
#pragma unroll
            for (int j = 0; j < 4; ++j) acc[i][j] = zero;

        short8 afc[2], bfc[4];
#pragma unroll
        for (int i = 0; i < 2; ++i)
            afc[i] = *(const short8*)(Ub16
                    + (size_t)(tr * 64 + wvr * 32 + i * 16 + lm) * NC + lk);
#pragma unroll
        for (int j = 0; j < 4; ++j)
            bfc[j] = *(const short8*)(Gb
                    + (size_t)(wvc * 64 + j * 16 + lm) * NC + lk);

#pragma unroll
        for (int kk = 0; kk < 256; kk += 32) {
            short8 afn[2], bfn[4];
            if (kk < 224) {
#pragma unroll
                for (int i = 0; i < 2; ++i)
                    afn[i] = *(const short8*)(Ub16
                            + (size_t)(tr * 64 + wvr * 32 + i * 16 + lm) * NC + kk + 32 + lk);
#pragma unroll
                for (int j = 0; j < 4; ++j)
                    bfn[j] = *(const short8*)(Gb
                            + (size_t)(wvc * 64 + j * 16 + lm) * NC + kk + 32 + lk);
            }
#pragma unroll
            for (int i = 0; i < 2; ++i)
#pragma unroll
                for (int j = 0; j < 4; ++j)
                    acc[i][j] = __builtin_amdgcn_mfma_f32_16x16x32_bf16(
                        afc[i], bfc[j], acc[i][j], 0, 0, 0);
            if (kk < 224) {
#pragma unroll
                for (int i = 0; i < 2; ++i) afc[i] = afn[i];
#pragma unroll
                for (int j = 0; j < 4; ++j) bfc[j] = bfn[j];
            }
        }
#pragma unroll
        for (int i = 0; i < 2; ++i)
#pragma unroll
            for (int j = 0; j < 4; ++j)
#pragma unroll
                for (int rr = 0; rr < 4; ++rr)
                    Ts[wvr * 32 + i * 16 + lh * 4 + rr]
                      [wvc * 64 + j * 16 + lm] = f2s(acc[i][j][rr]);
    }
    __syncthreads();

    // ---- stage 2: Qf = Ts . VT^T  (64 x 128, K=256, A from LDS, prefetch)
    {
        int qr = wave >> 1;       // 0..3: 16-row group
        int qc = wave & 1;        // 0..1: 64-col group
        floatx4 acc2[4];
#pragma unroll
        for (int j = 0; j < 4; ++j) acc2[j] = zero;

        short8 ac2, bc2[4];
        ac2 = *(const short8*)&Ts[qr * 16 + lm][lk];
#pragma unroll
        for (int j = 0; j < 4; ++j)
            bc2[j] = *(const short8*)(VTb16
                    + (size_t)(tc * 128 + qc * 64 + j * 16 + lm) * NC + lk);

#pragma unroll
        for (int kk = 0; kk < 256; kk += 32) {
            short8 an2, bn2[4];
            if (kk < 224) {
                an2 = *(const short8*)&Ts[qr * 16 + lm][kk + 32 + lk];
#pragma unroll
                for (int j = 0; j < 4; ++j)
                    bn2[j] = *(const short8*)(VTb16
                            + (size_t)(tc * 128 + qc * 64 + j * 16 + lm) * NC + kk + 32 + lk);
            }
#pragma unroll
            for (int j = 0; j < 4; ++j)
                acc2[j] = __builtin_amdgcn_mfma_f32_16x16x32_bf16(
                    ac2, bc2[j], acc2[j], 0, 0, 0);
            if (kk < 224) {
                ac2 = an2;
#pragma unroll
                for (int j = 0; j < 4; ++j) bc2[j] = bn2[j];
            }
        }

#pragma unroll
        for (int rr = 0; rr < 4; ++rr) {
            int cl = qr * 16 + lh * 4 + rr;          // 0..63
            int c = tr * 64 + cl;
            float u1c = u1v[c];
            float u2c = f2[cl];
            float scl = gamma[c] * rsqrtf(var[c] + BN_EPS) * (1.f / (float)NN);
#pragma unroll
            for (int j = 0; j < 4; ++j) {
                int cpl = qc * 64 + j * 16 + lm;     // 0..127
                int cp = tc * 128 + cpl;
                float v = acc2[j][rr] + u1c * f1[cpl]
                        + (u2c + (float)NN * u1c) * vbv[cp];
                QfB[(size_t)b * 65536 + (size_t)c * NC + cp] = f2s(v * scl);
            }
        }
    }
}

// ---------------------------------------------------------------------------
// out: out[c,n] = sum_c' Qf[c,c'] x[c',n] + C2[c] + x[c,n]   (unchanged)
// ---------------------------------------------------------------------------
__global__ __launch_bounds__(512, 2)
void out_kernel(const short* __restrict__ QfB, const float* __restrict__ C2g,
                const float* __restrict__ x, float* __restrict__ out)
{
    __shared__ short Xs[96][72];
    int blk = blockIdx.x;
    int b = blk >> 5;
    int n0 = (blk & 31) * 96;
    int t = threadIdx.x, lane = t & 63, wave = t >> 6;
    int lm = lane & 15, lh = lane >> 4, lk = lh * 8;
    int wr = wave >> 1, wc = wave & 1;
    const float* xb = x + (size_t)b * NC * NN;
    const short* Qb = QfB + (size_t)b * 65536;

    floatx4 zero = {0.f, 0.f, 0.f, 0.f};
    floatx4 acc[4][3];
#pragma unroll
    for (int i = 0; i < 4; ++i)
#pragma unroll
        for (int j = 0; j < 3; ++j) acc[i][j] = zero;

    int sn = t % 96, cgp = t / 96;   // valid for t < 384
    float xf[16];
    if (t < 384) {
#pragma unroll
        for (int j = 0; j < 16; ++j)
            xf[j] = xb[(size_t)(cgp * 16 + j) * NN + n0 + sn];
    }

#pragma unroll
    for (int kt = 0; kt < NC; kt += 64) {
        __syncthreads();
        short8 af2[2][4];
#pragma unroll
        for (int h = 0; h < 2; ++h)
#pragma unroll
            for (int i = 0; i < 4; ++i)
                af2[h][i] = *(const short8*)(Qb
                        + (size_t)(wr * 64 + i * 16 + lm) * 256 + kt + h * 32 + lk);
        if (t < 384) {
            short8 s0, s1;
#pragma unroll
            for (int j = 0; j < 8; ++j) {
                s0[j] = f2s(xf[j]);
                s1[j] = f2s(xf[8 + j]);
            }
            *(short8*)&Xs[sn][cgp * 16]     = s0;
            *(short8*)&Xs[sn][cgp * 16 + 8] = s1;
        }
        __syncthreads();
        if (t < 384 && kt < NC - 64) {
#pragma unroll
            for (int j = 0; j < 16; ++j)
                xf[j] = xb[(size_t)(kt + 64 + cgp * 16 + j) * NN + n0 + sn];
        }
#pragma unroll
        for (int h = 0; h < 2; ++h) {
            short8 bfr[3];
#pragma unroll
            for (int j = 0; j < 3; ++j)
                bfr[j] = *(const short8*)&Xs[wc * 48 + j * 16 + lm][h * 32 + lk];
#pragma unroll
            for (int i = 0; i < 4; ++i)
#pragma unroll
                for (int j = 0; j < 3; ++j)
                    acc[i][j] = __builtin_amdgcn_mfma_f32_16x16x32_bf16(
                        af2[h][i], bfr[j], acc[i][j], 0, 0, 0);
        }
    }

    float* Cf = out + (size_t)b * NC * NN;
#pragma unroll
    for (int i = 0; i < 4; ++i) {
#pragma unroll
        for (int rr = 0; rr < 4; ++rr) {
            int c = wr * 64 + i * 16 + lh * 4 + rr;
            float c2 = C2g[b * NC + c];
#pragma unroll
            for (int j = 0; j < 3; ++j) {
                size_t idx = (size_t)c * NN + n0 + wc * 48 + j * 16 + lm;
                Cf[idx] = acc[i][j][rr] + c2 + xb[idx];
            }
        }
    }
}

extern "C" void kernel_launch(void* const* d_in, const int* in_sizes, int n_in,
                              void* d_out, int out_size, void* d_ws, size_t ws_size,
                              hipStream_t stream)
{
    const float* x       = (const float*)d_in[0];
    const float* g_w     = (const float*)d_in[1];
    const float* g_b     = (const float*)d_in[2];
    const float* theta_w = (const float*)d_in[3];
    const float* theta_b = (const float*)d_in[4];
    const float* phi_w   = (const float*)d_in[5];
    const float* phi_b   = (const float*)d_in[6];
    const float* w_w     = (const float*)d_in[7];
    const float* w_b     = (const float*)d_in[8];
    const float* gamma   = (const float*)d_in[9];
    const float* beta    = (const float*)d_in[10];
    const float* mean    = (const float*)d_in[11];
    const float* var     = (const float*)d_in[12];
    (void)in_sizes; (void)n_in; (void)out_size; (void)ws_size;

    char* w = (char*)d_ws;
    float* sx    = (float*)w; w += (size_t)NB * NC * 4;               // 8 KB
    float* C2g   = (float*)w; w += (size_t)NB * NC * 4;               // 8 KB
    float* qv    = (float*)w; w += (size_t)NC * 4;                    // 1 KB
    float* u1v   = (float*)w; w += (size_t)NC * 4;                    // 1 KB
    float* vbv   = (float*)w; w += (size_t)NC * 4;                    // 1 KB
    w = (char*)(((size_t)w + 255) & ~(size_t)255);
    float* U     = (float*)w; w += (size_t)NC * NC * 4;               // 256 KB
    float* VT    = (float*)w; w += (size_t)NC * NC * 4;               // 256 KB
    short* Ub16  = (short*)w; w += (size_t)NC * NC * 2;               // 128 KB
    short* VTb16 = (short*)w; w += (size_t)NC * NC * 2;               // 128 KB
    float* G     = (float*)w; w += (size_t)NB * NC * NC * 4;          // 2 MB
    short* Gb16  = (short*)w; w += (size_t)NB * NC * NC * 2;          // 1 MB
    short* GpartS= (short*)w; w += (size_t)NB * NCH * NC * NC * 2;    // 32 MB
    short* QfB   = (short*)w; w += (size_t)NB * NC * NC * 2;          // 1 MB

    front_kernel<<<dim3(384), dim3(512), 0, stream>>>(x, GpartS, sx);

    gredUV_kernel<<<dim3(521), dim3(256), 0, stream>>>(
        GpartS, g_w, g_b, theta_w, theta_b, phi_w, phi_b, w_w,
        G, Gb16, U, Ub16, VT, VTb16, qv, u1v, vbv);

    qf_kernel<<<dim3(72), dim3(512), 0, stream>>>(
        G, Gb16, U, Ub16, VT, VTb16, qv, u1v, vbv, sx,
        phi_b, theta_b, w_b, gamma, beta, mean, var, QfB, C2g);

    out_kernel<<<dim3(256), dim3(512), 0, stream>>>(QfB, C2g, x, (float*)d_out);
}